// Round 7
// baseline (452.336 us; speedup 1.0000x reference)
//
#include <hip/hip_runtime.h>
#include <hip/hip_bf16.h>
#include <cstdint>
#include <cstddef>

typedef __bf16 bf16_t;
typedef __bf16 bf16x8 __attribute__((ext_vector_type(8)));
typedef float f32x4 __attribute__((ext_vector_type(4)));

#define B_SZ 32
#define H_SZ 56
#define W_SZ 56
#define N_TOK 3136
#define CH 128
#define M_TOT 100352

// bf16 weight workspace offsets (elements)
#define WOFF_FC1 0
#define WOFF_FC2 16384
#define WOFF_FC3 32768
#define WOFF_FC4 49152
#define WOFF_FC5 65536
#define WOFF_FC6 98304
#define WOFF_QW  131072
#define WOFF_KW  147456
#define WOFF_VW  163840
#define WTOT     180224

enum { A_FLAT = 0, A_WROLL, A_LN, A_BN };
enum { E_BIAS = 0, E_GELU, E_RES };

__device__ __forceinline__ float bf2f(bf16_t v) { return (float)v; }
__device__ __forceinline__ unsigned short bfbits(float v) {
    bf16_t b = (bf16_t)v; unsigned short u; __builtin_memcpy(&u, &b, 2); return u;
}

// ---------------------------------------------------------------------------
// Weight pre-convert: f32 -> bf16 in B-fragment layout [n][k].
// ---------------------------------------------------------------------------
__global__ __launch_bounds__(256)
void wcvt_k(const float* __restrict__ f1, const float* __restrict__ f2,
            const float* __restrict__ f3, const float* __restrict__ f4,
            const float* __restrict__ f5, const float* __restrict__ f6,
            const float* __restrict__ qw, const float* __restrict__ kw,
            const float* __restrict__ vw, bf16_t* __restrict__ wb)
{
    const int blk = blockIdx.x;
    const int tid = threadIdx.x;
    if (blk < 32) {
        __shared__ bf16_t T[64][72];
        const float* src; bf16_t* dst; int K, t;
        if (blk < 4)       { src = f1; dst = wb + WOFF_FC1; K = 128; t = blk; }
        else if (blk < 8)  { src = f2; dst = wb + WOFF_FC2; K = 128; t = blk - 4; }
        else if (blk < 12) { src = f3; dst = wb + WOFF_FC3; K = 128; t = blk - 8; }
        else if (blk < 16) { src = f4; dst = wb + WOFF_FC4; K = 128; t = blk - 12; }
        else if (blk < 24) { src = f5; dst = wb + WOFF_FC5; K = 256; t = blk - 16; }
        else               { src = f6; dst = wb + WOFF_FC6; K = 256; t = blk - 24; }
        const int ti = t >> 1;          // k-tile
        const int tj = t & 1;           // n-tile
        for (int it = tid; it < 64 * 16; it += 256) {
            const int r = it >> 4, c4 = it & 15;
            float4 u = *(const float4*)(src + (size_t)(ti * 64 + r) * 128 + tj * 64 + c4 * 4);
            T[c4 * 4 + 0][r] = (bf16_t)u.x;
            T[c4 * 4 + 1][r] = (bf16_t)u.y;
            T[c4 * 4 + 2][r] = (bf16_t)u.z;
            T[c4 * 4 + 3][r] = (bf16_t)u.w;
        }
        __syncthreads();
        for (int it = tid; it < 64 * 8; it += 256) {
            const int n = it >> 3, ck = it & 7;
            *(uint4*)(dst + (size_t)(tj * 64 + n) * K + ti * 64 + ck * 8) =
                *(const uint4*)(&T[n][ck * 8]);
        }
    } else {
        const float* src; bf16_t* dst;
        int t = blk - 32;
        if (t < 4)      { src = qw; dst = wb + WOFF_QW; }
        else if (t < 8) { src = kw; dst = wb + WOFF_KW; t -= 4; }
        else            { src = vw; dst = wb + WOFF_VW; t -= 8; }
        const int base = t * 4096 + tid * 16;
        float4 u0 = *(const float4*)(src + base);
        float4 u1 = *(const float4*)(src + base + 4);
        float4 u2 = *(const float4*)(src + base + 8);
        float4 u3 = *(const float4*)(src + base + 12);
        bf16_t o[16] = {(bf16_t)u0.x, (bf16_t)u0.y, (bf16_t)u0.z, (bf16_t)u0.w,
                        (bf16_t)u1.x, (bf16_t)u1.y, (bf16_t)u1.z, (bf16_t)u1.w,
                        (bf16_t)u2.x, (bf16_t)u2.y, (bf16_t)u2.z, (bf16_t)u2.w,
                        (bf16_t)u3.x, (bf16_t)u3.y, (bf16_t)u3.z, (bf16_t)u3.w};
        *(uint4*)(dst + base) = *(const uint4*)o;
        *(uint4*)(dst + base + 8) = *(const uint4*)(o + 8);
    }
}

// ---------------------------------------------------------------------------
// Transpose: x[B,N,C] f32 -> xT[B,C,N] bf16  AND  xbf[B,N,C] bf16.
// ---------------------------------------------------------------------------
__global__ __launch_bounds__(256)
void transpose_k(const float* __restrict__ x, bf16_t* __restrict__ xT,
                 bf16_t* __restrict__ xbf)
{
    __shared__ bf16_t T[128][70];
    const int tid = threadIdx.x;
    const int mbase = blockIdx.x * 64;
    const int bimg = mbase / N_TOK;
    const int n0 = mbase - bimg * N_TOK;
    for (int idx = tid; idx < 64 * 32; idx += 256) {
        const int tok = idx >> 5, cg = idx & 31;
        float4 u = *(const float4*)(x + (size_t)(mbase + tok) * CH + cg * 4);
        bf16_t t4[4] = {(bf16_t)u.x, (bf16_t)u.y, (bf16_t)u.z, (bf16_t)u.w};
        T[cg * 4 + 0][tok] = t4[0];
        T[cg * 4 + 1][tok] = t4[1];
        T[cg * 4 + 2][tok] = t4[2];
        T[cg * 4 + 3][tok] = t4[3];
        *(uint2*)(xbf + (size_t)(mbase + tok) * CH + cg * 4) = *(const uint2*)t4;
    }
    __syncthreads();
    const uint* T32 = (const uint*)&T[0][0]; // [128][35]
    for (int idx = tid; idx < 128 * 8; idx += 256) {
        const int c = idx >> 3, chunk = idx & 7;
        uint4 o;
        o.x = T32[c * 35 + chunk * 4 + 0];
        o.y = T32[c * 35 + chunk * 4 + 1];
        o.z = T32[c * 35 + chunk * 4 + 2];
        o.w = T32[c * 35 + chunk * 4 + 3];
        *(uint4*)(xT + ((size_t)(bimg * 128 + c)) * N_TOK + n0 + chunk * 8) = o;
    }
}

// ---------------------------------------------------------------------------
// Fused fc1+fc2 (branch 1): one block = one (b,h) row of 56 tokens.
// R7: staging lane remap (c = idx&127) -> As writes hit all 32 banks (was
// ~13-way conflict, 3.7M conflict-cycles/dispatch). Y stride 137 (scalar-only
// buffer, odd-ish stride -> epilogue writes 2-way instead of 4-way).
// ---------------------------------------------------------------------------
__global__ __launch_bounds__(256, 4)
void fc12_k(const bf16_t* __restrict__ xT, const bf16_t* __restrict__ xbf,
            const bf16_t* __restrict__ w1, const float* __restrict__ b1,
            const bf16_t* __restrict__ w2, const float* __restrict__ b2,
            bf16_t* __restrict__ out, float* __restrict__ rs1)
{
    __shared__ __align__(16) bf16_t As[64 * 136];
    __shared__ __align__(16) bf16_t Y[56 * 137];
    __shared__ float SS[112];
    const int tid = threadIdx.x;
    const int blk = blockIdx.x;          // bimg*56 + h
    const int bimg = blk / 56;
    const int h = blk - bimg * 56;
    const int nbase = h * 56;
    const int lane = tid & 63;
    const int wv = tid >> 6;
    const int qd = lane >> 4;
    const int mr = lane & 15;

    if (tid < 112) SS[tid] = 0.f;

    // ---- stage As[w][c] = roll_H(+c)(x)[h,w,c]  (lanes span c -> 2-way banks) ----
    for (int idx = tid; idx < 128 * 7; idx += 256) {
        const int c = idx & 127, chunk = idx >> 7;
        const int cm = (c >= 112) ? c - 112 : (c >= 56 ? c - 56 : c);
        int hs = h - cm; if (hs < 0) hs += 56;
        const bf16_t* src = xT + ((size_t)(bimg * 128 + c)) * N_TOK + hs * 56 + chunk * 8;
        uint4 u = *(const uint4*)src;
        const bf16_t* up = (const bf16_t*)&u;
#pragma unroll
        for (int j = 0; j < 8; ++j) As[(chunk * 8 + j) * 136 + c] = up[j];
    }
    __syncthreads();

    // ---- gemm1: y1 = GELU(As @ W1 + b1) -> Y (LDS) ----
    {
        const bf16_t* wbase = w1 + (size_t)(wv * 32 + mr) * 128 + qd * 8;
        bf16x8 bfr[4][2];
#pragma unroll
        for (int kt = 0; kt < 4; ++kt)
#pragma unroll
            for (int nt = 0; nt < 2; ++nt)
                bfr[kt][nt] = *(const bf16x8*)(wbase + (size_t)(nt * 16) * 128 + kt * 32);
        f32x4 acc[4][2];
#pragma unroll
        for (int i = 0; i < 4; ++i)
#pragma unroll
            for (int j = 0; j < 2; ++j) { f32x4 z = {0.f,0.f,0.f,0.f}; acc[i][j] = z; }
#pragma unroll
        for (int kt = 0; kt < 4; ++kt) {
            bf16x8 af[4];
#pragma unroll
            for (int mt = 0; mt < 4; ++mt)
                af[mt] = *(const bf16x8*)(&As[(mt * 16 + mr) * 136 + kt * 32 + qd * 8]);
#pragma unroll
            for (int mt = 0; mt < 4; ++mt)
#pragma unroll
                for (int nt = 0; nt < 2; ++nt)
                    acc[mt][nt] = __builtin_amdgcn_mfma_f32_16x16x32_bf16(
                        af[mt], bfr[kt][nt], acc[mt][nt], 0, 0, 0);
        }
#pragma unroll
        for (int mt = 0; mt < 4; ++mt)
#pragma unroll
            for (int nt = 0; nt < 2; ++nt) {
                const int col = wv * 32 + nt * 16 + mr;
                const float bb = b1[col];
#pragma unroll
                for (int r = 0; r < 4; ++r) {
                    const int row = mt * 16 + qd * 4 + r;
                    if (row < 56) {
                        float v = acc[mt][nt][r] + bb;
                        v = 0.5f * v * (1.f + erff(v * 0.70710678118654752f));
                        Y[row * 137 + col] = (bf16_t)v;
                    }
                }
            }
    }
    __syncthreads();

    // ---- roll-copy: As[w][c] = Y[(w - cm + 56) % 56][c] ----
    for (int idx = tid; idx < 56 * 128; idx += 256) {
        const int row = idx >> 7, c = idx & 127;
        const int cm = (c >= 112) ? c - 112 : (c >= 56 ? c - 56 : c);
        int ws = row - cm; if (ws < 0) ws += 56;
        As[row * 136 + c] = Y[ws * 137 + c];
    }
    __syncthreads();

    // ---- gemm2: out = As @ W2 + b2 + x; row (sum,sumsq) -> rs1 ----
    {
        const bf16_t* wbase = w2 + (size_t)(wv * 32 + mr) * 128 + qd * 8;
        bf16x8 bfr[4][2];
#pragma unroll
        for (int kt = 0; kt < 4; ++kt)
#pragma unroll
            for (int nt = 0; nt < 2; ++nt)
                bfr[kt][nt] = *(const bf16x8*)(wbase + (size_t)(nt * 16) * 128 + kt * 32);
        f32x4 acc[4][2];
#pragma unroll
        for (int i = 0; i < 4; ++i)
#pragma unroll
            for (int j = 0; j < 2; ++j) { f32x4 z = {0.f,0.f,0.f,0.f}; acc[i][j] = z; }
#pragma unroll
        for (int kt = 0; kt < 4; ++kt) {
            bf16x8 af[4];
#pragma unroll
            for (int mt = 0; mt < 4; ++mt)
                af[mt] = *(const bf16x8*)(&As[(mt * 16 + mr) * 136 + kt * 32 + qd * 8]);
#pragma unroll
            for (int mt = 0; mt < 4; ++mt)
#pragma unroll
                for (int nt = 0; nt < 2; ++nt)
                    acc[mt][nt] = __builtin_amdgcn_mfma_f32_16x16x32_bf16(
                        af[mt], bfr[kt][nt], acc[mt][nt], 0, 0, 0);
        }
#pragma unroll
        for (int mt = 0; mt < 4; ++mt) {
            float srow[4] = {0.f, 0.f, 0.f, 0.f};
            float qrow[4] = {0.f, 0.f, 0.f, 0.f};
#pragma unroll
            for (int nt = 0; nt < 2; ++nt) {
                const int col = wv * 32 + nt * 16 + mr;
                const float bb = b2[col];
#pragma unroll
                for (int r = 0; r < 4; ++r) {
                    const int row = mt * 16 + qd * 4 + r;
                    if (row < 56) {
                        const size_t rowg = (size_t)bimg * N_TOK + nbase + row;
                        float v = acc[mt][nt][r] + bb + bf2f(xbf[rowg * CH + col]);
                        out[rowg * CH + col] = (bf16_t)v;
                        srow[r] += v; qrow[r] += v * v;
                    }
                }
            }
#pragma unroll
            for (int r = 0; r < 4; ++r) {
                const int row = mt * 16 + qd * 4 + r;
                float s = srow[r], q = qrow[r];
                s += __shfl_xor(s, 1); q += __shfl_xor(q, 1);
                s += __shfl_xor(s, 2); q += __shfl_xor(q, 2);
                s += __shfl_xor(s, 4); q += __shfl_xor(q, 4);
                s += __shfl_xor(s, 8); q += __shfl_xor(q, 8);
                if (mr == 0 && row < 56) {
                    atomicAdd(&SS[row], s);
                    atomicAdd(&SS[56 + row], q);
                }
            }
        }
    }
    __syncthreads();
    if (tid < 56) {
        const size_t rowg = (size_t)bimg * N_TOK + nbase + tid;
        rs1[2 * rowg] = SS[tid];
        rs1[2 * rowg + 1] = SS[56 + tid];
    }
}

// ---------------------------------------------------------------------------
// MFMA GEMM: out[M,128] = f(A) @ W + bias (+epilogue). 64x128 tile.
// R7: A_FLAT/A_WROLL staging lane remap (c = idx&127) -> scalar As writes
// cover all 32 banks (was 16-way conflict). Reads untouched.
// ---------------------------------------------------------------------------
template<int AMODE, int KHALVES, int EPI, int WDIR, int OTRANS, int OF32, int STATS>
__global__ __launch_bounds__(256)
void gemm_k(const bf16_t* __restrict__ A0, const bf16_t* __restrict__ A1,
            const bf16_t* __restrict__ Wt, const float* __restrict__ bias,
            const bf16_t* __restrict__ resid,
            const float* __restrict__ rowst,
            const float* __restrict__ lnw, const float* __restrict__ lnb,
            const float* __restrict__ bnp,
            float* __restrict__ rsout,
            void* __restrict__ outv)
{
    __shared__ __align__(16) char smem[17920]; // As [64][136] bf16 / scratch
    bf16_t* As = (bf16_t*)smem;
    const int tid = threadIdx.x;
    const int mbase = blockIdx.x * 64;
    const int bimg = mbase / N_TOK;
    const int n0 = mbase - bimg * N_TOK;
    const int lane = tid & 63;
    const int wv = tid >> 6;
    const int qd = lane >> 4;
    const int mr = lane & 15;
    const int KS = 128 * KHALVES;

    f32x4 acc[4][2];
#pragma unroll
    for (int i = 0; i < 4; ++i)
#pragma unroll
        for (int j = 0; j < 2; ++j) { f32x4 z = {0.f,0.f,0.f,0.f}; acc[i][j] = z; }

    for (int kh = 0; kh < KHALVES; ++kh) {
        if (kh) __syncthreads();
        // ---- stage A tile [64 tok][128 k] ----
        if (AMODE == A_FLAT || AMODE == A_WROLL) {
            for (int idx = tid; idx < 128 * 8; idx += 256) {
                const int c = idx & 127, chunk = idx >> 7;
                const int cm = (c >= 112) ? c - 112 : (c >= 56 ? c - 56 : c);
                const bf16_t* crow = A0 + ((size_t)(bimg * 128 + c)) * N_TOK;
                if (AMODE == A_FLAT) {
                    int t = n0 + chunk * 8 + N_TOK - 56 * cm;
                    if (t >= N_TOK) t -= N_TOK;
                    uint4 u = *(const uint4*)(crow + t);
                    const bf16_t* up = (const bf16_t*)&u;
#pragma unroll
                    for (int j = 0; j < 8; ++j) As[(chunk * 8 + j) * 136 + c] = up[j];
                } else {
                    const int nl = n0 + chunk * 8;
                    const int h = nl / 56;
                    const int w0 = nl - h * 56;
                    int ws = (WDIR > 0) ? (w0 + cm) : (w0 + 56 - cm);
                    if (ws >= 56) ws -= 56;
                    const bf16_t* hrow = crow + h * 56;
                    if (ws <= 48) {
                        uint4 u = *(const uint4*)(hrow + ws);
                        const bf16_t* up = (const bf16_t*)&u;
#pragma unroll
                        for (int j = 0; j < 8; ++j) As[(chunk * 8 + j) * 136 + c] = up[j];
                    } else {
#pragma unroll
                        for (int j = 0; j < 8; ++j) {
                            int wj = ws + j; if (wj >= 56) wj -= 56;
                            As[(chunk * 8 + j) * 136 + c] = hrow[wj];
                        }
                    }
                }
            }
        } else if (AMODE == A_LN) {
            for (int idx = tid; idx < 64 * 16; idx += 256) {
                const int row = idx >> 4, ck = idx & 15;
                const int rowg = mbase + row;
                const bf16_t* src = kh ? A1 : A0;
                uint4 u = *(const uint4*)(src + (size_t)rowg * CH + ck * 8);
                const bf16_t* up = (const bf16_t*)&u;
                const float s12 = rowst[2 * rowg] + bnp[2 * rowg];
                const float q12 = rowst[2 * rowg + 1] + bnp[2 * rowg + 1];
                const float mean = s12 * (1.f / 256.f);
                const float rstd = rsqrtf(q12 * (1.f / 256.f) - mean * mean + 1e-5f);
                const int cabs = kh * 128 + ck * 8;
                bf16_t t[8];
#pragma unroll
                for (int j = 0; j < 8; ++j) {
                    float v = (bf2f(up[j]) - mean) * rstd;
                    v = v * lnw[cabs + j] + lnb[cabs + j];
                    t[j] = (bf16_t)v;
                }
                *(uint4*)(&As[row * 136 + ck * 8]) = *(const uint4*)t;
            }
        } else { // A_BN
            for (int idx = tid; idx < 64 * 16; idx += 256) {
                const int row = idx >> 4, ck = idx & 15;
                const int rowg = mbase + row;
                if (kh == 0) {
                    uint4 u = *(const uint4*)(A0 + (size_t)rowg * CH + ck * 8);
                    *(uint4*)(&As[row * 136 + ck * 8]) = u;
                } else {
                    uint4 u = *(const uint4*)(A1 + (size_t)rowg * CH + ck * 8);
                    const bf16_t* up = (const bf16_t*)&u;
                    bf16_t t[8];
#pragma unroll
                    for (int j = 0; j < 8; ++j) {
                        const int c = ck * 8 + j;
                        float z = fmaxf(0.f, bf2f(up[j]) * bnp[c] + bnp[128 + c]);
                        t[j] = (bf16_t)(z * bnp[256 + c] + bnp[384 + c]);
                    }
                    *(uint4*)(&As[row * 136 + ck * 8]) = *(const uint4*)t;
                }
            }
        }
        __syncthreads();
        // ---- MFMA: hoisted B loads (one L2 exposure), then kt loop ----
        const bf16_t* wbase = Wt + (size_t)(wv * 32 + mr) * KS + kh * 128 + qd * 8;
        bf16x8 bfr[4][2];
#pragma unroll
        for (int kt = 0; kt < 4; ++kt)
#pragma unroll
            for (int nt = 0; nt < 2; ++nt)
                bfr[kt][nt] = *(const bf16x8*)(wbase + (size_t)(nt * 16) * KS + kt * 32);
#pragma unroll
        for (int kt = 0; kt < 4; ++kt) {
            bf16x8 af[4];
#pragma unroll
            for (int mt = 0; mt < 4; ++mt)
                af[mt] = *(const bf16x8*)(&As[(mt * 16 + mr) * 136 + kt * 32 + qd * 8]);
#pragma unroll
            for (int mt = 0; mt < 4; ++mt)
#pragma unroll
                for (int nt = 0; nt < 2; ++nt)
                    acc[mt][nt] = __builtin_amdgcn_mfma_f32_16x16x32_bf16(
                        af[mt], bfr[kt][nt], acc[mt][nt], 0, 0, 0);
        }
    }
    // ---- epilogue ----
    if (OTRANS) {
        __syncthreads();               // As reads complete
        uint* T32 = (uint*)smem;       // [128][35]
#pragma unroll
        for (int mt = 0; mt < 4; ++mt)
#pragma unroll
            for (int nt = 0; nt < 2; ++nt) {
                const int col = wv * 32 + nt * 16 + mr;
                const float bb = bias[col];
#pragma unroll
                for (int rp = 0; rp < 2; ++rp) {
                    float v0 = acc[mt][nt][2 * rp] + bb;
                    float v1 = acc[mt][nt][2 * rp + 1] + bb;
                    if (EPI == E_GELU) {
                        v0 = 0.5f * v0 * (1.f + erff(v0 * 0.70710678118654752f));
                        v1 = 0.5f * v1 * (1.f + erff(v1 * 0.70710678118654752f));
                    }
                    T32[col * 35 + mt * 8 + qd * 2 + rp] =
                        (uint)bfbits(v0) | ((uint)bfbits(v1) << 16);
                }
            }
        __syncthreads();
        const int c = tid >> 1, half = tid & 1;
        uint r[16];
#pragma unroll
        for (int j = 0; j < 16; ++j) r[j] = T32[c * 35 + half * 16 + j];
        bf16_t* op = (bf16_t*)outv + ((size_t)(bimg * 128 + c)) * N_TOK + n0 + half * 32;
        uint4 o0 = {r[0], r[1], r[2], r[3]};
        uint4 o1 = {r[4], r[5], r[6], r[7]};
        uint4 o2 = {r[8], r[9], r[10], r[11]};
        uint4 o3 = {r[12], r[13], r[14], r[15]};
        ((uint4*)op)[0] = o0; ((uint4*)op)[1] = o1;
        ((uint4*)op)[2] = o2; ((uint4*)op)[3] = o3;
    } else {
        float srow[4][4], qrow[4][4];
        if (STATS) {
#pragma unroll
            for (int mt = 0; mt < 4; ++mt)
#pragma unroll
                for (int r = 0; r < 4; ++r) { srow[mt][r] = 0.f; qrow[mt][r] = 0.f; }
        }
#pragma unroll
        for (int mt = 0; mt < 4; ++mt)
#pragma unroll
            for (int nt = 0; nt < 2; ++nt) {
                const int col = wv * 32 + nt * 16 + mr;
                const float bb = bias[col];
#pragma unroll
                for (int r = 0; r < 4; ++r) {
                    const int rowg = mbase + mt * 16 + qd * 4 + r;
                    float v = acc[mt][nt][r] + bb;
                    if (EPI == E_GELU) v = 0.5f * v * (1.f + erff(v * 0.70710678118654752f));
                    if (EPI == E_RES)  v += bf2f(resid[(size_t)rowg * CH + col]);
                    if (STATS) { srow[mt][r] += v; qrow[mt][r] += v * v; }
                    if (OF32) ((float*)outv)[(size_t)rowg * CH + col] = v;
                    else ((bf16_t*)outv)[(size_t)rowg * CH + col] = (bf16_t)v;
                }
            }
        if (STATS) {
            __syncthreads();           // all As reads done -> smem reusable
            float* SQ = (float*)smem;  // [128]: sums [0,64), sumsq [64,128)
            if (tid < 128) SQ[tid] = 0.f;
            __syncthreads();
#pragma unroll
            for (int mt = 0; mt < 4; ++mt)
#pragma unroll
                for (int r = 0; r < 4; ++r) {
                    float s = srow[mt][r], q = qrow[mt][r];
                    s += __shfl_xor(s, 1); q += __shfl_xor(q, 1);
                    s += __shfl_xor(s, 2); q += __shfl_xor(q, 2);
                    s += __shfl_xor(s, 4); q += __shfl_xor(q, 4);
                    s += __shfl_xor(s, 8); q += __shfl_xor(q, 8);
                    if (mr == 0) {
                        const int row = mt * 16 + qd * 4 + r;
                        atomicAdd(&SQ[row], s);
                        atomicAdd(&SQ[64 + row], q);
                    }
                }
            __syncthreads();
            if (tid < 64) {
                rsout[2 * (mbase + tid)] = SQ[tid];
                rsout[2 * (mbase + tid) + 1] = SQ[64 + tid];
            }
        }
    }
}

// ---------------------------------------------------------------------------
// Fused q/k/v: stage x-tile once; input is xbf (bf16, identical numerics).
// ---------------------------------------------------------------------------
__global__ __launch_bounds__(256)
void qkv_k(const bf16_t* __restrict__ xbf, const bf16_t* __restrict__ wb,
           const float* __restrict__ qb, const float* __restrict__ kb,
           const float* __restrict__ vb,
           bf16_t* __restrict__ qo, bf16_t* __restrict__ ko, bf16_t* __restrict__ vo)
{
    __shared__ __align__(16) bf16_t As[64 * 136];
    const int tid = threadIdx.x;
    const int mbase = blockIdx.x * 64;
    const int lane = tid & 63;
    const int wv = tid >> 6;
    const int qd = lane >> 4;
    const int mr = lane & 15;

    for (int idx = tid; idx < 64 * 16; idx += 256) {
        const int row = idx >> 4, ck = idx & 15;
        uint4 u = *(const uint4*)(xbf + (size_t)(mbase + row) * CH + ck * 8);
        *(uint4*)(&As[row * 136 + ck * 8]) = u;
    }
    __syncthreads();
    bf16x8 af[4][4];
#pragma unroll
    for (int kt = 0; kt < 4; ++kt)
#pragma unroll
        for (int mt = 0; mt < 4; ++mt)
            af[kt][mt] = *(const bf16x8*)(&As[(mt * 16 + mr) * 136 + kt * 32 + qd * 8]);

    const int woffs[3] = {WOFF_QW, WOFF_KW, WOFF_VW};
    const float* bs3[3] = {qb, kb, vb};
    bf16_t* os3[3] = {qo, ko, vo};
#pragma unroll
    for (int s = 0; s < 3; ++s) {
        const bf16_t* wbase = wb + woffs[s] + (size_t)(wv * 32 + mr) * 128 + qd * 8;
        f32x4 acc[4][2];
#pragma unroll
        for (int i = 0; i < 4; ++i)
#pragma unroll
            for (int j = 0; j < 2; ++j) { f32x4 z = {0.f,0.f,0.f,0.f}; acc[i][j] = z; }
#pragma unroll
        for (int kt = 0; kt < 4; ++kt) {
            bf16x8 bfr[2];
#pragma unroll
            for (int nt = 0; nt < 2; ++nt)
                bfr[nt] = *(const bf16x8*)(wbase + (nt * 16) * 128 + kt * 32);
#pragma unroll
            for (int mt = 0; mt < 4; ++mt)
#pragma unroll
                for (int nt = 0; nt < 2; ++nt)
                    acc[mt][nt] = __builtin_amdgcn_mfma_f32_16x16x32_bf16(
                        af[kt][mt], bfr[nt], acc[mt][nt], 0, 0, 0);
        }
        bf16_t* out = os3[s];
#pragma unroll
        for (int mt = 0; mt < 4; ++mt)
#pragma unroll
            for (int nt = 0; nt < 2; ++nt) {
                const int col = wv * 32 + nt * 16 + mr;
                const float bb = bs3[s][col];
#pragma unroll
                for (int r = 0; r < 4; ++r) {
                    const int rowg = mbase + mt * 16 + qd * 4 + r;
                    out[(size_t)rowg * CH + col] = (bf16_t)(acc[mt][nt][r] + bb);
                }
            }
    }
}

// ---------------------------------------------------------------------------
// MFMA window attention (R3 v4 structure — empirical best).
// ---------------------------------------------------------------------------
__global__ __launch_bounds__(256, 6)
void attn_k(const bf16_t* __restrict__ qg, const bf16_t* __restrict__ kg,
            const bf16_t* __restrict__ vg, bf16_t* __restrict__ og,
            float* __restrict__ partial)
{
    __shared__ __align__(16) char smem[27136];
    bf16_t* Vt = (bf16_t*)smem;               // [128][68] V^T
    bf16_t* Ps = (bf16_t*)(smem + 17408);     // [64][68] P
    float* bnacc = (float*)(smem + 26112);    // [256]
    bf16_t* Os = (bf16_t*)smem;               // [64][136] overlay (after PV)

    const int tid = threadIdx.x;
    const int blk = blockIdx.x;
    const int b = blk >> 6;
    const int wy = (blk >> 3) & 7;
    const int wx = blk & 7;
    const int lane = tid & 63;
    const int wv = tid >> 6;
    const int qd = lane >> 4;
    const int mr = lane & 15;

    bnacc[tid] = 0.f;

    // ---- A: issue V loads (tok = tid&15, ck = tid>>4) ----
    const int vi0 = tid & 15;
    const int vck = tid >> 4;
    uint4 vld[4];
#pragma unroll
    for (int it = 0; it < 4; ++it) {
        const int i = vi0 + it * 16;
        uint4 uv = {0, 0, 0, 0};
        if (i < 49) {
            const int n = (wy * 7 + i / 7) * 56 + wx * 7 + (i % 7);
            uv = *(const uint4*)(vg + ((size_t)b * N_TOK + n) * CH + vck * 8);
        }
        vld[it] = uv;
    }

    // ---- B: Q/K fragment loads + QK^T ----
    const int qrow = wv * 16 + mr;
    const int qc = qrow < 49 ? qrow : 48;
    const bf16_t* qptr = qg + ((size_t)b * N_TOK +
                               (wy * 7 + qc / 7) * 56 + wx * 7 + (qc % 7)) * CH + qd * 8;
    bf16x8 aq[4];
#pragma unroll
    for (int kt = 0; kt < 4; ++kt)
        aq[kt] = *(const bf16x8*)(qptr + kt * 32);

    f32x4 sacc[4];
#pragma unroll
    for (int nt = 0; nt < 4; ++nt) {
        const int krow = nt * 16 + mr;
        const int kc = krow < 49 ? krow : 48;
        const bf16_t* kptr = kg + ((size_t)b * N_TOK +
                                   (wy * 7 + kc / 7) * 56 + wx * 7 + (kc % 7)) * CH + qd * 8;
        f32x4 a = {0.f, 0.f, 0.f, 0.f};
#pragma unroll
        for (int kt = 0; kt < 4; ++kt) {
            bf16x8 bk = *(const bf16x8*)(kptr + kt * 32);
            a = __builtin_amdgcn_mfma_f32_16x16x32_bf16(aq[kt], bk, a, 0, 0, 0);
        }
        sacc[nt] = a;
    }

    // ---- C: direct transposed V write: Vt[ch][tok] ----
#pragma unroll
    for (int it = 0; it < 4; ++it) {
        const int i = vi0 + it * 16;
        const bf16_t* vp = (const bf16_t*)&vld[it];
#pragma unroll
        for (int j = 0; j < 8; ++j)
            Vt[(vck * 8 + j) * 68 + i] = vp[j];
    }

    // ---- D: in-register softmax + P write ----
    {
        const float SCALE = 0.088388347648318447f;
#pragma unroll
        for (int nt = 0; nt < 4; ++nt) {
            const bool bad = (nt * 16 + mr) > 48;
#pragma unroll
            for (int r = 0; r < 4; ++r)
                sacc[nt][r] = bad ? -1e30f : sacc[nt][r] * SCALE;
        }
        float pv[4][4];
        float inv[4];
#pragma unroll
        for (int r = 0; r < 4; ++r) {
            float m = fmaxf(fmaxf(sacc[0][r], sacc[1][r]), fmaxf(sacc[2][r], sacc[3][r]));
            m = fmaxf(m, __shfl_xor(m, 1));
            m = fmaxf(m, __shfl_xor(m, 2));
            m = fmaxf(m, __shfl_xor(m, 4));
            m = fmaxf(m, __shfl_xor(m, 8));
#pragma unroll
            for (int nt = 0; nt < 4; ++nt) pv[nt][r] = __expf(sacc[nt][r] - m);
            float s = (pv[0][r] + pv[1][r]) + (pv[2][r] + pv[3][r]);
            s += __shfl_xor(s, 1);
            s += __shfl_xor(s, 2);
            s += __shfl_xor(s, 4);
            s += __shfl_xor(s, 8);
            inv[r] = 1.f / s;
        }
#pragma unroll
        for (int nt = 0; nt < 4; ++nt)
#pragma unroll
            for (int r = 0; r < 4; ++r)
                Ps[(wv * 16 + qd * 4 + r) * 68 + nt * 16 + mr] = (bf16_t)(pv[nt][r] * inv[r]);
    }
    __syncthreads();   // b1: Vt (+P) ready

    // ---- E: PV MFMA ----
    bf16x8 ap[2];
    ap[0] = *(const bf16x8*)(&Ps[(wv * 16 + mr) * 68 + qd * 8]);
    ap[1] = *(const bf16x8*)(&Ps[(wv * 16 + mr) * 68 + 32 + qd * 8]);
    f32x4 oacc[8];
#pragma unroll
    for (int nt = 0; nt < 8; ++nt) {
        f32x4 a = {0.f, 0.f, 0.f, 0.f};
#pragma unroll
        for (int kt = 0; kt < 2; ++kt) {
            bf16x8 bv = *(const bf16x8*)(&Vt[(nt * 16 + mr) * 68 + kt * 32 + qd * 8]);
            a = __builtin_amdgcn_mfma_f32_16x16x32_bf16(ap[kt], bv, a, 0, 0, 0);
        }
        oacc[nt] = a;
    }

    // ---- F: BN partials ----
#pragma unroll
    for (int nt = 0; nt < 8; ++nt) {
        const int c = nt * 16 + mr;
        float s = 0.f, sq = 0.f;
#pragma unroll
        for (int r = 0; r < 4; ++r) {
            const int q = wv * 16 + qd * 4 + r;
            if (q < 49) { const float v = oacc[nt][r]; s += v; sq += v * v; }
        }
        s += __shfl_xor(s, 16); sq += __shfl_xor(sq, 16);
        s += __shfl_xor(s, 32); sq += __shfl_xor(sq, 32);
        if (qd == 0) { atomicAdd(&bnacc[c], s); atomicAdd(&bnacc[128 + c], sq); }
    }
    __syncthreads();   // b2: Vt/Ps reads + atomics done -> Os overlay safe

    // ---- G: O -> LDS [64][136] ----
#pragma unroll
    for (int nt = 0; nt < 8; ++nt) {
        const int c = nt * 16 + mr;
#pragma unroll
        for (int r = 0; r < 4; ++r) {
            const int q = wv * 16 + qd * 4 + r;
            Os[q * 136 + c] = (bf16_t)oacc[nt][r];
        }
    }
    __syncthreads();   // b3

    // ---- H: coalesced uint4 stores + BN partial out ----
    for (int idx = tid; idx < 49 * 16; idx += 256) {
        const int row = idx >> 4, u = idx & 15;
        const int n = (wy * 7 + row / 7) * 56 + wx * 7 + (row % 7);
        *(uint4*)(og + ((size_t)b * N_TOK + n) * CH + u * 8) =
            *(const uint4*)(&Os[row * 136 + u * 8]);
    }
    partial[(size_t)blk * 256 + tid] = bnacc[tid];
}

// ---------------------------------------------------------------------------
__global__ __launch_bounds__(256)
void bnreduce_k(const float* __restrict__ partial, float* __restrict__ accum)
{
    const int t = threadIdx.x;
    const int r0 = blockIdx.x * 16;
    float s = 0.f;
#pragma unroll
    for (int r = 0; r < 16; ++r) s += partial[(size_t)(r0 + r) * 256 + t];
    atomicAdd(&accum[t], s);
}

__global__ __launch_bounds__(256)
void bnstats2_k(const bf16_t* __restrict__ att, const float* __restrict__ g1,
                const float* __restrict__ b1, float* __restrict__ accum)
{
    __shared__ float ls[256], lq[256];
    const int c = threadIdx.x & 127;
    const int half = threadIdx.x >> 7;
    const float m = accum[c] * (1.f / (float)M_TOT);
    const float var = accum[128 + c] * (1.f / (float)M_TOT) - m * m;
    const float rstd = rsqrtf(var + 1e-5f);
    const float scl = g1[c] * rstd;
    const float sh = b1[c] - m * scl;
    const size_t rowbase = (size_t)blockIdx.x * 196;
    float s = 0.f, sq = 0.f;
    for (int r = half; r < 196; r += 2) {
        float z = fmaxf(0.f, bf2f(att[(rowbase + r) * CH + c]) * scl + sh);
        s += z; sq += z * z;
    }
    ls[threadIdx.x] = s; lq[threadIdx.x] = sq;
    __syncthreads();
    if (threadIdx.x < 128) {
        atomicAdd(&accum[256 + c], ls[threadIdx.x] + ls[threadIdx.x + 128]);
        atomicAdd(&accum[384 + c], lq[threadIdx.x] + lq[threadIdx.x + 128]);
    }
}

__global__ void bnparams_k(const float* __restrict__ accum,
                           const float* __restrict__ g1, const float* __restrict__ b1,
                           const float* __restrict__ g2, const float* __restrict__ b2,
                           float* __restrict__ bnp)
{
    const int c = threadIdx.x;
    const float inv = 1.f / (float)M_TOT;
    float m1 = accum[c] * inv;
    float v1 = accum[128 + c] * inv - m1 * m1;
    float rs1 = rsqrtf(v1 + 1e-5f);
    float s1 = g1[c] * rs1;
    float sh1 = b1[c] - m1 * s1;
    float m2 = accum[256 + c] * inv;
    float v2 = accum[384 + c] * inv - m2 * m2;
    float rs2 = rsqrtf(v2 + 1e-5f);
    float s2 = g2[c] * rs2;
    float sh2 = b2[c] - m2 * s2;
    bnp[c] = s1; bnp[128 + c] = sh1; bnp[256 + c] = s2; bnp[384 + c] = sh2;
}

__global__ void zero_k(float* __restrict__ p) { p[threadIdx.x] = 0.f; }

// ---------------------------------------------------------------------------
extern "C" void kernel_launch(void* const* d_in, const int* in_sizes, int n_in,
                              void* d_out, int out_size, void* d_ws, size_t ws_size,
                              hipStream_t stream)
{
    (void)in_sizes; (void)n_in; (void)out_size; (void)ws_size;
    const float* x     = (const float*)d_in[0];
    const float* fc1_w = (const float*)d_in[1];
    const float* fc1_b = (const float*)d_in[2];
    const float* fc2_w = (const float*)d_in[3];
    const float* fc2_b = (const float*)d_in[4];
    const float* fc3_w = (const float*)d_in[5];
    const float* fc3_b = (const float*)d_in[6];
    const float* fc4_w = (const float*)d_in[7];
    const float* fc4_b = (const float*)d_in[8];
    const float* fc5_w = (const float*)d_in[9];
    const float* fc5_b = (const float*)d_in[10];
    const float* fc6_w = (const float*)d_in[11];
    const float* fc6_b = (const float*)d_in[12];
    const float* ln_w  = (const float*)d_in[13];
    const float* ln_b  = (const float*)d_in[14];
    const float* q_w   = (const float*)d_in[15];
    const float* q_b   = (const float*)d_in[16];
    const float* k_w   = (const float*)d_in[17];
    const float* k_b   = (const float*)d_in[18];
    const float* v_w   = (const float*)d_in[19];
    const float* v_b   = (const float*)d_in[20];
    const float* bn1_g = (const float*)d_in[21];
    const float* bn1_b = (const float*)d_in[22];
    const float* bn2_g = (const float*)d_in[23];
    const float* bn2_b = (const float*)d_in[24];

    char* ws = (char*)d_ws;
    const size_t SZB = (size_t)M_TOT * CH * sizeof(bf16_t); // 25.7 MB
    bf16_t* bufA = (bf16_t*)(ws);            // xT -> q -> attn out
    bf16_t* bufB = (bf16_t*)(ws + SZB);      // y3T -> x1
    bf16_t* bufC = (bf16_t*)(ws + 2 * SZB);  // x_1+x -> k
    bf16_t* bufD = (bf16_t*)(ws + 3 * SZB);  // x_2+x -> v
    bf16_t* xbf  = (bf16_t*)(ws + 4 * SZB);  // bf16 copy of x
    float*  rs1  = (float*)(ws + 5 * SZB);                 // [2*M] branch-1 partials
    float*  rs2  = rs1 + 2 * M_TOT;                        // [2*M] branch-2 partials
    float*  accum = rs2 + 2 * M_TOT;
    float*  bnp  = accum + 512;
    float*  partial = bnp + 512;             // [2048][256] (2 MB)
    bf16_t* wbuf = (bf16_t*)(partial + 2048 * 256); // preconverted weights (0.36 MB)

    const dim3 blk(256);
    const int GG = M_TOT / 64; // 1568

    zero_k<<<1, 512, 0, stream>>>(accum);
    wcvt_k<<<44, blk, 0, stream>>>(fc1_w, fc2_w, fc3_w, fc4_w, fc5_w, fc6_w,
                                   q_w, k_w, v_w, wbuf);
    transpose_k<<<GG, blk, 0, stream>>>(x, bufA, xbf);
    // branch 1 FUSED: fc1 (H-roll +c) + GELU + fc2 (W-roll +c) + x -> bufC; rs1
    fc12_k<<<B_SZ * 56, blk, 0, stream>>>(
        bufA, xbf, wbuf + WOFF_FC1, fc1_b, wbuf + WOFF_FC2, fc2_b, bufC, rs1);
    // branch 2: fc3 (W-roll -c) + GELU -> y3T [C,N]
    gemm_k<A_WROLL, 1, E_GELU, 1, 1, 0, 0><<<GG, blk, 0, stream>>>(
        bufA, nullptr, wbuf + WOFF_FC3, fc3_b, nullptr, nullptr, nullptr, nullptr,
        nullptr, nullptr, bufB);
    // fc4 (H-roll +c on y3T) + x -> bufD; rs2 partials
    gemm_k<A_FLAT, 1, E_RES, 0, 0, 0, 1><<<GG, blk, 0, stream>>>(
        bufB, nullptr, wbuf + WOFF_FC4, fc4_b, xbf, nullptr, nullptr, nullptr,
        nullptr, rs2, bufD);
    // fc5: LN (stats from rs1+rs2) + (+x) -> bufB = x1
    gemm_k<A_LN, 2, E_RES, 0, 0, 0, 0><<<GG, blk, 0, stream>>>(
        bufC, bufD, wbuf + WOFF_FC5, fc5_b, xbf, rs1, ln_w, ln_b,
        rs2, nullptr, bufB);
    // fused qkv (from xbf)
    qkv_k<<<GG, blk, 0, stream>>>(xbf, wbuf, q_b, k_b, v_b, bufA, bufC, bufD);
    // MFMA window attention (+ BN pass-1 partials) -> bufA
    attn_k<<<B_SZ * 64, blk, 0, stream>>>(bufA, bufC, bufD, bufA, partial);
    bnreduce_k<<<128, blk, 0, stream>>>(partial, accum);
    bnstats2_k<<<512, blk, 0, stream>>>(bufA, bn1_g, bn1_b, accum);
    bnparams_k<<<1, 128, 0, stream>>>(accum, bn1_g, bn1_b, bn2_g, bn2_b, bnp);
    // fc6 on [x1 | bn2(relu(bn1(att)))] -> d_out (f32)
    gemm_k<A_BN, 2, E_BIAS, 0, 0, 1, 0><<<GG, blk, 0, stream>>>(
        bufB, bufA, wbuf + WOFF_FC6, fc6_b, nullptr, nullptr, nullptr, nullptr,
        bnp, nullptr, d_out);
}

// Round 8
// 413.533 us; speedup vs baseline: 1.0938x; 1.0938x over previous
//
#include <hip/hip_runtime.h>
#include <hip/hip_bf16.h>
#include <cstdint>
#include <cstddef>

typedef __bf16 bf16_t;
typedef __bf16 bf16x8 __attribute__((ext_vector_type(8)));
typedef float f32x4 __attribute__((ext_vector_type(4)));

#define B_SZ 32
#define H_SZ 56
#define W_SZ 56
#define N_TOK 3136
#define CH 128
#define M_TOT 100352

// bf16 weight workspace offsets (elements)
#define WOFF_FC1 0
#define WOFF_FC2 16384
#define WOFF_FC3 32768
#define WOFF_FC4 49152
#define WOFF_FC5 65536
#define WOFF_FC6 98304
#define WOFF_QW  131072
#define WOFF_KW  147456
#define WOFF_VW  163840
#define WTOT     180224

enum { A_FLAT = 0, A_WROLL, A_LN, A_BN };
enum { E_BIAS = 0, E_GELU, E_RES };

__device__ __forceinline__ float bf2f(bf16_t v) { return (float)v; }
__device__ __forceinline__ unsigned short bfbits(float v) {
    bf16_t b = (bf16_t)v; unsigned short u; __builtin_memcpy(&u, &b, 2); return u;
}

// ---------------------------------------------------------------------------
// Weight pre-convert: f32 -> bf16 in B-fragment layout [n][k].
// ---------------------------------------------------------------------------
__global__ __launch_bounds__(256)
void wcvt_k(const float* __restrict__ f1, const float* __restrict__ f2,
            const float* __restrict__ f3, const float* __restrict__ f4,
            const float* __restrict__ f5, const float* __restrict__ f6,
            const float* __restrict__ qw, const float* __restrict__ kw,
            const float* __restrict__ vw, bf16_t* __restrict__ wb)
{
    const int blk = blockIdx.x;
    const int tid = threadIdx.x;
    if (blk < 32) {
        __shared__ bf16_t T[64][72];
        const float* src; bf16_t* dst; int K, t;
        if (blk < 4)       { src = f1; dst = wb + WOFF_FC1; K = 128; t = blk; }
        else if (blk < 8)  { src = f2; dst = wb + WOFF_FC2; K = 128; t = blk - 4; }
        else if (blk < 12) { src = f3; dst = wb + WOFF_FC3; K = 128; t = blk - 8; }
        else if (blk < 16) { src = f4; dst = wb + WOFF_FC4; K = 128; t = blk - 12; }
        else if (blk < 24) { src = f5; dst = wb + WOFF_FC5; K = 256; t = blk - 16; }
        else               { src = f6; dst = wb + WOFF_FC6; K = 256; t = blk - 24; }
        const int ti = t >> 1;          // k-tile
        const int tj = t & 1;           // n-tile
        for (int it = tid; it < 64 * 16; it += 256) {
            const int r = it >> 4, c4 = it & 15;
            float4 u = *(const float4*)(src + (size_t)(ti * 64 + r) * 128 + tj * 64 + c4 * 4);
            T[c4 * 4 + 0][r] = (bf16_t)u.x;
            T[c4 * 4 + 1][r] = (bf16_t)u.y;
            T[c4 * 4 + 2][r] = (bf16_t)u.z;
            T[c4 * 4 + 3][r] = (bf16_t)u.w;
        }
        __syncthreads();
        for (int it = tid; it < 64 * 8; it += 256) {
            const int n = it >> 3, ck = it & 7;
            *(uint4*)(dst + (size_t)(tj * 64 + n) * K + ti * 64 + ck * 8) =
                *(const uint4*)(&T[n][ck * 8]);
        }
    } else {
        const float* src; bf16_t* dst;
        int t = blk - 32;
        if (t < 4)      { src = qw; dst = wb + WOFF_QW; }
        else if (t < 8) { src = kw; dst = wb + WOFF_KW; t -= 4; }
        else            { src = vw; dst = wb + WOFF_VW; t -= 8; }
        const int base = t * 4096 + tid * 16;
        float4 u0 = *(const float4*)(src + base);
        float4 u1 = *(const float4*)(src + base + 4);
        float4 u2 = *(const float4*)(src + base + 8);
        float4 u3 = *(const float4*)(src + base + 12);
        bf16_t o[16] = {(bf16_t)u0.x, (bf16_t)u0.y, (bf16_t)u0.z, (bf16_t)u0.w,
                        (bf16_t)u1.x, (bf16_t)u1.y, (bf16_t)u1.z, (bf16_t)u1.w,
                        (bf16_t)u2.x, (bf16_t)u2.y, (bf16_t)u2.z, (bf16_t)u2.w,
                        (bf16_t)u3.x, (bf16_t)u3.y, (bf16_t)u3.z, (bf16_t)u3.w};
        *(uint4*)(dst + base) = *(const uint4*)o;
        *(uint4*)(dst + base + 8) = *(const uint4*)(o + 8);
    }
}

// ---------------------------------------------------------------------------
// Transpose: x[B,N,C] f32 -> xT[B,C,N] bf16  AND  xbf[B,N,C] bf16.
// ---------------------------------------------------------------------------
__global__ __launch_bounds__(256)
void transpose_k(const float* __restrict__ x, bf16_t* __restrict__ xT,
                 bf16_t* __restrict__ xbf)
{
    __shared__ bf16_t T[128][70];
    const int tid = threadIdx.x;
    const int mbase = blockIdx.x * 64;
    const int bimg = mbase / N_TOK;
    const int n0 = mbase - bimg * N_TOK;
    for (int idx = tid; idx < 64 * 32; idx += 256) {
        const int tok = idx >> 5, cg = idx & 31;
        float4 u = *(const float4*)(x + (size_t)(mbase + tok) * CH + cg * 4);
        bf16_t t4[4] = {(bf16_t)u.x, (bf16_t)u.y, (bf16_t)u.z, (bf16_t)u.w};
        T[cg * 4 + 0][tok] = t4[0];
        T[cg * 4 + 1][tok] = t4[1];
        T[cg * 4 + 2][tok] = t4[2];
        T[cg * 4 + 3][tok] = t4[3];
        *(uint2*)(xbf + (size_t)(mbase + tok) * CH + cg * 4) = *(const uint2*)t4;
    }
    __syncthreads();
    const uint* T32 = (const uint*)&T[0][0]; // [128][35]
    for (int idx = tid; idx < 128 * 8; idx += 256) {
        const int c = idx >> 3, chunk = idx & 7;
        uint4 o;
        o.x = T32[c * 35 + chunk * 4 + 0];
        o.y = T32[c * 35 + chunk * 4 + 1];
        o.z = T32[c * 35 + chunk * 4 + 2];
        o.w = T32[c * 35 + chunk * 4 + 3];
        *(uint4*)(xT + ((size_t)(bimg * 128 + c)) * N_TOK + n0 + chunk * 8) = o;
    }
}

// ---------------------------------------------------------------------------
// Fused fc1+fc2 (branch 1): one block = one (b,h) row of 56 tokens.
// (R8: staging reverted to R6 coalesced form — R7 remap traded a non-critical
// LDS conflict for scattered global reads, -5%.)
// ---------------------------------------------------------------------------
__global__ __launch_bounds__(256, 4)
void fc12_k(const bf16_t* __restrict__ xT, const bf16_t* __restrict__ xbf,
            const bf16_t* __restrict__ w1, const float* __restrict__ b1,
            const bf16_t* __restrict__ w2, const float* __restrict__ b2,
            bf16_t* __restrict__ out, float* __restrict__ rs1)
{
    __shared__ __align__(16) bf16_t As[64 * 136];
    __shared__ __align__(16) bf16_t Y[56 * 136];
    __shared__ float SS[112];
    const int tid = threadIdx.x;
    const int blk = blockIdx.x;          // bimg*56 + h
    const int bimg = blk / 56;
    const int h = blk - bimg * 56;
    const int nbase = h * 56;
    const int lane = tid & 63;
    const int wv = tid >> 6;
    const int qd = lane >> 4;
    const int mr = lane & 15;

    if (tid < 112) SS[tid] = 0.f;

    // ---- stage As[w][c] = roll_H(+c)(x)[h,w,c]  (coalesced per-row chunks) ----
    for (int idx = tid; idx < 128 * 7; idx += 256) {
        const int c = idx / 7, chunk = idx - c * 7;
        const int cm = (c >= 112) ? c - 112 : (c >= 56 ? c - 56 : c);
        int hs = h - cm; if (hs < 0) hs += 56;
        const bf16_t* src = xT + ((size_t)(bimg * 128 + c)) * N_TOK + hs * 56 + chunk * 8;
        uint4 u = *(const uint4*)src;
        const bf16_t* up = (const bf16_t*)&u;
#pragma unroll
        for (int j = 0; j < 8; ++j) As[(chunk * 8 + j) * 136 + c] = up[j];
    }
    __syncthreads();

    // ---- gemm1: y1 = GELU(As @ W1 + b1) -> Y (LDS) ----
    {
        const bf16_t* wbase = w1 + (size_t)(wv * 32 + mr) * 128 + qd * 8;
        bf16x8 bfr[4][2];
#pragma unroll
        for (int kt = 0; kt < 4; ++kt)
#pragma unroll
            for (int nt = 0; nt < 2; ++nt)
                bfr[kt][nt] = *(const bf16x8*)(wbase + (size_t)(nt * 16) * 128 + kt * 32);
        f32x4 acc[4][2];
#pragma unroll
        for (int i = 0; i < 4; ++i)
#pragma unroll
            for (int j = 0; j < 2; ++j) { f32x4 z = {0.f,0.f,0.f,0.f}; acc[i][j] = z; }
#pragma unroll
        for (int kt = 0; kt < 4; ++kt) {
            bf16x8 af[4];
#pragma unroll
            for (int mt = 0; mt < 4; ++mt)
                af[mt] = *(const bf16x8*)(&As[(mt * 16 + mr) * 136 + kt * 32 + qd * 8]);
#pragma unroll
            for (int mt = 0; mt < 4; ++mt)
#pragma unroll
                for (int nt = 0; nt < 2; ++nt)
                    acc[mt][nt] = __builtin_amdgcn_mfma_f32_16x16x32_bf16(
                        af[mt], bfr[kt][nt], acc[mt][nt], 0, 0, 0);
        }
#pragma unroll
        for (int mt = 0; mt < 4; ++mt)
#pragma unroll
            for (int nt = 0; nt < 2; ++nt) {
                const int col = wv * 32 + nt * 16 + mr;
                const float bb = b1[col];
#pragma unroll
                for (int r = 0; r < 4; ++r) {
                    const int row = mt * 16 + qd * 4 + r;
                    if (row < 56) {
                        float v = acc[mt][nt][r] + bb;
                        v = 0.5f * v * (1.f + erff(v * 0.70710678118654752f));
                        Y[row * 136 + col] = (bf16_t)v;
                    }
                }
            }
    }
    __syncthreads();

    // ---- roll-copy: As[w][c] = Y[(w - cm + 56) % 56][c] ----
    for (int idx = tid; idx < 56 * 128; idx += 256) {
        const int row = idx >> 7, c = idx & 127;
        const int cm = (c >= 112) ? c - 112 : (c >= 56 ? c - 56 : c);
        int ws = row - cm; if (ws < 0) ws += 56;
        As[row * 136 + c] = Y[ws * 136 + c];
    }
    __syncthreads();

    // ---- gemm2: out = As @ W2 + b2 + x; row (sum,sumsq) -> rs1 ----
    {
        const bf16_t* wbase = w2 + (size_t)(wv * 32 + mr) * 128 + qd * 8;
        bf16x8 bfr[4][2];
#pragma unroll
        for (int kt = 0; kt < 4; ++kt)
#pragma unroll
            for (int nt = 0; nt < 2; ++nt)
                bfr[kt][nt] = *(const bf16x8*)(wbase + (size_t)(nt * 16) * 128 + kt * 32);
        f32x4 acc[4][2];
#pragma unroll
        for (int i = 0; i < 4; ++i)
#pragma unroll
            for (int j = 0; j < 2; ++j) { f32x4 z = {0.f,0.f,0.f,0.f}; acc[i][j] = z; }
#pragma unroll
        for (int kt = 0; kt < 4; ++kt) {
            bf16x8 af[4];
#pragma unroll
            for (int mt = 0; mt < 4; ++mt)
                af[mt] = *(const bf16x8*)(&As[(mt * 16 + mr) * 136 + kt * 32 + qd * 8]);
#pragma unroll
            for (int mt = 0; mt < 4; ++mt)
#pragma unroll
                for (int nt = 0; nt < 2; ++nt)
                    acc[mt][nt] = __builtin_amdgcn_mfma_f32_16x16x32_bf16(
                        af[mt], bfr[kt][nt], acc[mt][nt], 0, 0, 0);
        }
#pragma unroll
        for (int mt = 0; mt < 4; ++mt) {
            float srow[4] = {0.f, 0.f, 0.f, 0.f};
            float qrow[4] = {0.f, 0.f, 0.f, 0.f};
#pragma unroll
            for (int nt = 0; nt < 2; ++nt) {
                const int col = wv * 32 + nt * 16 + mr;
                const float bb = b2[col];
#pragma unroll
                for (int r = 0; r < 4; ++r) {
                    const int row = mt * 16 + qd * 4 + r;
                    if (row < 56) {
                        const size_t rowg = (size_t)bimg * N_TOK + nbase + row;
                        float v = acc[mt][nt][r] + bb + bf2f(xbf[rowg * CH + col]);
                        out[rowg * CH + col] = (bf16_t)v;
                        srow[r] += v; qrow[r] += v * v;
                    }
                }
            }
#pragma unroll
            for (int r = 0; r < 4; ++r) {
                const int row = mt * 16 + qd * 4 + r;
                float s = srow[r], q = qrow[r];
                s += __shfl_xor(s, 1); q += __shfl_xor(q, 1);
                s += __shfl_xor(s, 2); q += __shfl_xor(q, 2);
                s += __shfl_xor(s, 4); q += __shfl_xor(q, 4);
                s += __shfl_xor(s, 8); q += __shfl_xor(q, 8);
                if (mr == 0 && row < 56) {
                    atomicAdd(&SS[row], s);
                    atomicAdd(&SS[56 + row], q);
                }
            }
        }
    }
    __syncthreads();
    if (tid < 56) {
        const size_t rowg = (size_t)bimg * N_TOK + nbase + tid;
        rs1[2 * rowg] = SS[tid];
        rs1[2 * rowg + 1] = SS[56 + tid];
    }
}

// ---------------------------------------------------------------------------
// MFMA GEMM: out[M,128] = f(A) @ W + bias (+epilogue). 64x128 tile.
// (R8: A staging reverted to R6 coalesced form.)
// ---------------------------------------------------------------------------
template<int AMODE, int KHALVES, int EPI, int WDIR, int OTRANS, int OF32, int STATS>
__global__ __launch_bounds__(256)
void gemm_k(const bf16_t* __restrict__ A0, const bf16_t* __restrict__ A1,
            const bf16_t* __restrict__ Wt, const float* __restrict__ bias,
            const bf16_t* __restrict__ resid,
            const float* __restrict__ rowst,
            const float* __restrict__ lnw, const float* __restrict__ lnb,
            const float* __restrict__ bnp,
            float* __restrict__ rsout,
            void* __restrict__ outv)
{
    __shared__ __align__(16) char smem[17920]; // As [64][136] bf16 / scratch
    bf16_t* As = (bf16_t*)smem;
    const int tid = threadIdx.x;
    const int mbase = blockIdx.x * 64;
    const int bimg = mbase / N_TOK;
    const int n0 = mbase - bimg * N_TOK;
    const int lane = tid & 63;
    const int wv = tid >> 6;
    const int qd = lane >> 4;
    const int mr = lane & 15;
    const int KS = 128 * KHALVES;

    f32x4 acc[4][2];
#pragma unroll
    for (int i = 0; i < 4; ++i)
#pragma unroll
        for (int j = 0; j < 2; ++j) { f32x4 z = {0.f,0.f,0.f,0.f}; acc[i][j] = z; }

    for (int kh = 0; kh < KHALVES; ++kh) {
        if (kh) __syncthreads();
        // ---- stage A tile [64 tok][128 k] ----
        if (AMODE == A_FLAT || AMODE == A_WROLL) {
            for (int idx = tid; idx < 128 * 8; idx += 256) {
                const int c = idx >> 3, chunk = idx & 7;
                const int cm = (c >= 112) ? c - 112 : (c >= 56 ? c - 56 : c);
                const bf16_t* crow = A0 + ((size_t)(bimg * 128 + c)) * N_TOK;
                if (AMODE == A_FLAT) {
                    int t = n0 + chunk * 8 + N_TOK - 56 * cm;
                    if (t >= N_TOK) t -= N_TOK;
                    uint4 u = *(const uint4*)(crow + t);
                    const bf16_t* up = (const bf16_t*)&u;
#pragma unroll
                    for (int j = 0; j < 8; ++j) As[(chunk * 8 + j) * 136 + c] = up[j];
                } else {
                    const int nl = n0 + chunk * 8;
                    const int h = nl / 56;
                    const int w0 = nl - h * 56;
                    int ws = (WDIR > 0) ? (w0 + cm) : (w0 + 56 - cm);
                    if (ws >= 56) ws -= 56;
                    const bf16_t* hrow = crow + h * 56;
                    if (ws <= 48) {
                        uint4 u = *(const uint4*)(hrow + ws);
                        const bf16_t* up = (const bf16_t*)&u;
#pragma unroll
                        for (int j = 0; j < 8; ++j) As[(chunk * 8 + j) * 136 + c] = up[j];
                    } else {
#pragma unroll
                        for (int j = 0; j < 8; ++j) {
                            int wj = ws + j; if (wj >= 56) wj -= 56;
                            As[(chunk * 8 + j) * 136 + c] = hrow[wj];
                        }
                    }
                }
            }
        } else if (AMODE == A_LN) {
            for (int idx = tid; idx < 64 * 16; idx += 256) {
                const int row = idx >> 4, ck = idx & 15;
                const int rowg = mbase + row;
                const bf16_t* src = kh ? A1 : A0;
                uint4 u = *(const uint4*)(src + (size_t)rowg * CH + ck * 8);
                const bf16_t* up = (const bf16_t*)&u;
                const float s12 = rowst[2 * rowg] + bnp[2 * rowg];
                const float q12 = rowst[2 * rowg + 1] + bnp[2 * rowg + 1];
                const float mean = s12 * (1.f / 256.f);
                const float rstd = rsqrtf(q12 * (1.f / 256.f) - mean * mean + 1e-5f);
                const int cabs = kh * 128 + ck * 8;
                bf16_t t[8];
#pragma unroll
                for (int j = 0; j < 8; ++j) {
                    float v = (bf2f(up[j]) - mean) * rstd;
                    v = v * lnw[cabs + j] + lnb[cabs + j];
                    t[j] = (bf16_t)v;
                }
                *(uint4*)(&As[row * 136 + ck * 8]) = *(const uint4*)t;
            }
        } else { // A_BN
            for (int idx = tid; idx < 64 * 16; idx += 256) {
                const int row = idx >> 4, ck = idx & 15;
                const int rowg = mbase + row;
                if (kh == 0) {
                    uint4 u = *(const uint4*)(A0 + (size_t)rowg * CH + ck * 8);
                    *(uint4*)(&As[row * 136 + ck * 8]) = u;
                } else {
                    uint4 u = *(const uint4*)(A1 + (size_t)rowg * CH + ck * 8);
                    const bf16_t* up = (const bf16_t*)&u;
                    bf16_t t[8];
#pragma unroll
                    for (int j = 0; j < 8; ++j) {
                        const int c = ck * 8 + j;
                        float z = fmaxf(0.f, bf2f(up[j]) * bnp[c] + bnp[128 + c]);
                        t[j] = (bf16_t)(z * bnp[256 + c] + bnp[384 + c]);
                    }
                    *(uint4*)(&As[row * 136 + ck * 8]) = *(const uint4*)t;
                }
            }
        }
        __syncthreads();
        // ---- MFMA: hoisted B loads (one L2 exposure), then kt loop ----
        const bf16_t* wbase = Wt + (size_t)(wv * 32 + mr) * KS + kh * 128 + qd * 8;
        bf16x8 bfr[4][2];
#pragma unroll
        for (int kt = 0; kt < 4; ++kt)
#pragma unroll
            for (int nt = 0; nt < 2; ++nt)
                bfr[kt][nt] = *(const bf16x8*)(wbase + (size_t)(nt * 16) * KS + kt * 32);
#pragma unroll
        for (int kt = 0; kt < 4; ++kt) {
            bf16x8 af[4];
#pragma unroll
            for (int mt = 0; mt < 4; ++mt)
                af[mt] = *(const bf16x8*)(&As[(mt * 16 + mr) * 136 + kt * 32 + qd * 8]);
#pragma unroll
            for (int mt = 0; mt < 4; ++mt)
#pragma unroll
                for (int nt = 0; nt < 2; ++nt)
                    acc[mt][nt] = __builtin_amdgcn_mfma_f32_16x16x32_bf16(
                        af[mt], bfr[kt][nt], acc[mt][nt], 0, 0, 0);
        }
    }
    // ---- epilogue ----
    if (OTRANS) {
        __syncthreads();               // As reads complete
        uint* T32 = (uint*)smem;       // [128][35]
#pragma unroll
        for (int mt = 0; mt < 4; ++mt)
#pragma unroll
            for (int nt = 0; nt < 2; ++nt) {
                const int col = wv * 32 + nt * 16 + mr;
                const float bb = bias[col];
#pragma unroll
                for (int rp = 0; rp < 2; ++rp) {
                    float v0 = acc[mt][nt][2 * rp] + bb;
                    float v1 = acc[mt][nt][2 * rp + 1] + bb;
                    if (EPI == E_GELU) {
                        v0 = 0.5f * v0 * (1.f + erff(v0 * 0.70710678118654752f));
                        v1 = 0.5f * v1 * (1.f + erff(v1 * 0.70710678118654752f));
                    }
                    T32[col * 35 + mt * 8 + qd * 2 + rp] =
                        (uint)bfbits(v0) | ((uint)bfbits(v1) << 16);
                }
            }
        __syncthreads();
        const int c = tid >> 1, half = tid & 1;
        uint r[16];
#pragma unroll
        for (int j = 0; j < 16; ++j) r[j] = T32[c * 35 + half * 16 + j];
        bf16_t* op = (bf16_t*)outv + ((size_t)(bimg * 128 + c)) * N_TOK + n0 + half * 32;
        uint4 o0 = {r[0], r[1], r[2], r[3]};
        uint4 o1 = {r[4], r[5], r[6], r[7]};
        uint4 o2 = {r[8], r[9], r[10], r[11]};
        uint4 o3 = {r[12], r[13], r[14], r[15]};
        ((uint4*)op)[0] = o0; ((uint4*)op)[1] = o1;
        ((uint4*)op)[2] = o2; ((uint4*)op)[3] = o3;
    } else {
        float srow[4][4], qrow[4][4];
        if (STATS) {
#pragma unroll
            for (int mt = 0; mt < 4; ++mt)
#pragma unroll
                for (int r = 0; r < 4; ++r) { srow[mt][r] = 0.f; qrow[mt][r] = 0.f; }
        }
#pragma unroll
        for (int mt = 0; mt < 4; ++mt)
#pragma unroll
            for (int nt = 0; nt < 2; ++nt) {
                const int col = wv * 32 + nt * 16 + mr;
                const float bb = bias[col];
#pragma unroll
                for (int r = 0; r < 4; ++r) {
                    const int rowg = mbase + mt * 16 + qd * 4 + r;
                    float v = acc[mt][nt][r] + bb;
                    if (EPI == E_GELU) v = 0.5f * v * (1.f + erff(v * 0.70710678118654752f));
                    if (EPI == E_RES)  v += bf2f(resid[(size_t)rowg * CH + col]);
                    if (STATS) { srow[mt][r] += v; qrow[mt][r] += v * v; }
                    if (OF32) ((float*)outv)[(size_t)rowg * CH + col] = v;
                    else ((bf16_t*)outv)[(size_t)rowg * CH + col] = (bf16_t)v;
                }
            }
        if (STATS) {
            __syncthreads();           // all As reads done -> smem reusable
            float* SQ = (float*)smem;  // [128]: sums [0,64), sumsq [64,128)
            if (tid < 128) SQ[tid] = 0.f;
            __syncthreads();
#pragma unroll
            for (int mt = 0; mt < 4; ++mt)
#pragma unroll
                for (int r = 0; r < 4; ++r) {
                    float s = srow[mt][r], q = qrow[mt][r];
                    s += __shfl_xor(s, 1); q += __shfl_xor(q, 1);
                    s += __shfl_xor(s, 2); q += __shfl_xor(q, 2);
                    s += __shfl_xor(s, 4); q += __shfl_xor(q, 4);
                    s += __shfl_xor(s, 8); q += __shfl_xor(q, 8);
                    if (mr == 0) {
                        const int row = mt * 16 + qd * 4 + r;
                        atomicAdd(&SQ[row], s);
                        atomicAdd(&SQ[64 + row], q);
                    }
                }
            __syncthreads();
            if (tid < 64) {
                rsout[2 * (mbase + tid)] = SQ[tid];
                rsout[2 * (mbase + tid) + 1] = SQ[64 + tid];
            }
        }
    }
}

// ---------------------------------------------------------------------------
// FUSED qkv + window attention: one block per 7x7 window.
// Eliminates the q/k/v global round trip (~145 MB of HBM traffic):
//   stage x window -> 3 MFMA gemms (Q->LDS, K->LDS, V->regs) vs L2-hot
//   weights -> QK^T from LDS -> in-register softmax -> Vt/P overlay -> PV
//   -> BN partials -> coalesced O store.
// LDS 53248 B -> 3 blocks/CU (12 waves). MFMA work 4x the old attn_k but
// MfmaUtil was 3% -- compute is free; traffic is the currency.
//   [0,17408)      Xs [64][136]  -> P [64][68] overlay
//   [17408,34816)  Qs [64][136]  -> Os [64][136] overlay
//   [34816,52224)  Ks [64][136]  -> Vt [128][68] overlay
//   [52224,53248)  bnacc f32[256]
// ---------------------------------------------------------------------------
__global__ __launch_bounds__(256, 3)
void qkvattn_k(const bf16_t* __restrict__ xbf, const bf16_t* __restrict__ wb,
               const float* __restrict__ qb, const float* __restrict__ kb,
               const float* __restrict__ vb,
               bf16_t* __restrict__ og, float* __restrict__ partial)
{
    __shared__ __align__(16) char smem[53248];
    bf16_t* Xs = (bf16_t*)smem;               // [64][136]
    bf16_t* Ps = (bf16_t*)smem;               // [64][68] overlay
    bf16_t* Qs = (bf16_t*)(smem + 17408);     // [64][136]
    bf16_t* Os = (bf16_t*)(smem + 17408);     // [64][136] overlay
    bf16_t* Ks = (bf16_t*)(smem + 34816);     // [64][136]
    bf16_t* Vt = (bf16_t*)(smem + 34816);     // [128][68] overlay
    float* bnacc = (float*)(smem + 52224);    // [256]

    const int tid = threadIdx.x;
    const int blk = blockIdx.x;
    const int b = blk >> 6;
    const int wy = (blk >> 3) & 7;
    const int wx = blk & 7;
    const int lane = tid & 63;
    const int wv = tid >> 6;
    const int qd = lane >> 4;
    const int mr = lane & 15;

    bnacc[tid] = 0.f;

    // ---- stage x window [64 tok][128 ch], rows >= 49 zero ----
    for (int idx = tid; idx < 64 * 16; idx += 256) {
        const int row = idx >> 4, ck = idx & 15;
        uint4 u = {0, 0, 0, 0};
        if (row < 49) {
            const int n = (wy * 7 + row / 7) * 56 + wx * 7 + (row % 7);
            u = *(const uint4*)(xbf + ((size_t)b * N_TOK + n) * CH + ck * 8);
        }
        *(uint4*)(&Xs[row * 136 + ck * 8]) = u;
    }
    __syncthreads();   // b1: Xs ready

    // ---- A fragments (shared by Q/K/V gemms) ----
    bf16x8 af[4][4];
#pragma unroll
    for (int kt = 0; kt < 4; ++kt)
#pragma unroll
        for (int mt = 0; mt < 4; ++mt)
            af[kt][mt] = *(const bf16x8*)(&Xs[(mt * 16 + mr) * 136 + kt * 32 + qd * 8]);

    // ---- Q gemm -> Qs, K gemm -> Ks ----
    {
        const int woffs2[2] = {WOFF_QW, WOFF_KW};
        const float* bs2[2] = {qb, kb};
        bf16_t* os2[2] = {Qs, Ks};
#pragma unroll
        for (int s = 0; s < 2; ++s) {
            const bf16_t* wbase = wb + woffs2[s] + (size_t)(wv * 32 + mr) * 128 + qd * 8;
            bf16x8 bfr[4][2];
#pragma unroll
            for (int kt = 0; kt < 4; ++kt)
#pragma unroll
                for (int nt = 0; nt < 2; ++nt)
                    bfr[kt][nt] = *(const bf16x8*)(wbase + (nt * 16) * 128 + kt * 32);
            f32x4 acc[4][2];
#pragma unroll
            for (int i = 0; i < 4; ++i)
#pragma unroll
                for (int j = 0; j < 2; ++j) { f32x4 z = {0.f,0.f,0.f,0.f}; acc[i][j] = z; }
#pragma unroll
            for (int kt = 0; kt < 4; ++kt)
#pragma unroll
                for (int mt = 0; mt < 4; ++mt)
#pragma unroll
                    for (int nt = 0; nt < 2; ++nt)
                        acc[mt][nt] = __builtin_amdgcn_mfma_f32_16x16x32_bf16(
                            af[kt][mt], bfr[kt][nt], acc[mt][nt], 0, 0, 0);
            bf16_t* dst = os2[s];
#pragma unroll
            for (int mt = 0; mt < 4; ++mt)
#pragma unroll
                for (int nt = 0; nt < 2; ++nt) {
                    const int col = wv * 32 + nt * 16 + mr;
                    const float bb = bs2[s][col];
#pragma unroll
                    for (int r = 0; r < 4; ++r) {
                        const int row = mt * 16 + qd * 4 + r;
                        dst[row * 136 + col] = (bf16_t)(acc[mt][nt][r] + bb);
                    }
                }
        }
    }

    // ---- V gemm -> registers (written to Vt after Ks is dead) ----
    f32x4 vacc[4][2];
    {
        const bf16_t* wbase = wb + WOFF_VW + (size_t)(wv * 32 + mr) * 128 + qd * 8;
        bf16x8 bfr[4][2];
#pragma unroll
        for (int kt = 0; kt < 4; ++kt)
#pragma unroll
            for (int nt = 0; nt < 2; ++nt)
                bfr[kt][nt] = *(const bf16x8*)(wbase + (nt * 16) * 128 + kt * 32);
#pragma unroll
        for (int i = 0; i < 4; ++i)
#pragma unroll
            for (int j = 0; j < 2; ++j) { f32x4 z = {0.f,0.f,0.f,0.f}; vacc[i][j] = z; }
#pragma unroll
        for (int kt = 0; kt < 4; ++kt)
#pragma unroll
            for (int mt = 0; mt < 4; ++mt)
#pragma unroll
                for (int nt = 0; nt < 2; ++nt)
                    vacc[mt][nt] = __builtin_amdgcn_mfma_f32_16x16x32_bf16(
                        af[kt][mt], bfr[kt][nt], vacc[mt][nt], 0, 0, 0);
    }
    __syncthreads();   // b2: Qs, Ks ready

    // ---- QK^T from LDS ----
    bf16x8 aq[4];
#pragma unroll
    for (int kt = 0; kt < 4; ++kt)
        aq[kt] = *(const bf16x8*)(&Qs[(wv * 16 + mr) * 136 + kt * 32 + qd * 8]);
    f32x4 sacc[4];
#pragma unroll
    for (int nt = 0; nt < 4; ++nt) {
        f32x4 a = {0.f, 0.f, 0.f, 0.f};
#pragma unroll
        for (int kt = 0; kt < 4; ++kt) {
            bf16x8 bk = *(const bf16x8*)(&Ks[(nt * 16 + mr) * 136 + kt * 32 + qd * 8]);
            a = __builtin_amdgcn_mfma_f32_16x16x32_bf16(aq[kt], bk, a, 0, 0, 0);
        }
        sacc[nt] = a;
    }

    // ---- in-register softmax ----
    float pv[4][4];
    float inv[4];
    {
        const float SCALE = 0.088388347648318447f;
#pragma unroll
        for (int nt = 0; nt < 4; ++nt) {
            const bool bad = (nt * 16 + mr) > 48;
#pragma unroll
            for (int r = 0; r < 4; ++r)
                sacc[nt][r] = bad ? -1e30f : sacc[nt][r] * SCALE;
        }
#pragma unroll
        for (int r = 0; r < 4; ++r) {
            float m = fmaxf(fmaxf(sacc[0][r], sacc[1][r]), fmaxf(sacc[2][r], sacc[3][r]));
            m = fmaxf(m, __shfl_xor(m, 1));
            m = fmaxf(m, __shfl_xor(m, 2));
            m = fmaxf(m, __shfl_xor(m, 4));
            m = fmaxf(m, __shfl_xor(m, 8));
#pragma unroll
            for (int nt = 0; nt < 4; ++nt) pv[nt][r] = __expf(sacc[nt][r] - m);
            float s = (pv[0][r] + pv[1][r]) + (pv[2][r] + pv[3][r]);
            s += __shfl_xor(s, 1);
            s += __shfl_xor(s, 2);
            s += __shfl_xor(s, 4);
            s += __shfl_xor(s, 8);
            inv[r] = 1.f / s;
        }
    }
    __syncthreads();   // b3: Qs/Ks/Xs reads done -> Vt/P overlays safe

    // ---- Vt (over Ks) from vacc; P (over Xs) ----
#pragma unroll
    for (int mt = 0; mt < 4; ++mt)
#pragma unroll
        for (int nt = 0; nt < 2; ++nt) {
            const int c = wv * 32 + nt * 16 + mr;
            const float bb = vb[c];
#pragma unroll
            for (int r = 0; r < 4; ++r) {
                const int tok = mt * 16 + qd * 4 + r;
                Vt[c * 68 + tok] = (bf16_t)(vacc[mt][nt][r] + bb);
            }
        }
#pragma unroll
    for (int nt = 0; nt < 4; ++nt)
#pragma unroll
        for (int r = 0; r < 4; ++r)
            Ps[(wv * 16 + qd * 4 + r) * 68 + nt * 16 + mr] = (bf16_t)(pv[nt][r] * inv[r]);
    __syncthreads();   // b4: Vt + P ready

    // ---- PV MFMA ----
    bf16x8 ap[2];
    ap[0] = *(const bf16x8*)(&Ps[(wv * 16 + mr) * 68 + qd * 8]);
    ap[1] = *(const bf16x8*)(&Ps[(wv * 16 + mr) * 68 + 32 + qd * 8]);
    f32x4 oacc[8];
#pragma unroll
    for (int nt = 0; nt < 8; ++nt) {
        f32x4 a = {0.f, 0.f, 0.f, 0.f};
#pragma unroll
        for (int kt = 0; kt < 2; ++kt) {
            bf16x8 bv = *(const bf16x8*)(&Vt[(nt * 16 + mr) * 68 + kt * 32 + qd * 8]);
            a = __builtin_amdgcn_mfma_f32_16x16x32_bf16(ap[kt], bv, a, 0, 0, 0);
        }
        oacc[nt] = a;
    }

    // ---- BN partials ----
#pragma unroll
    for (int nt = 0; nt < 8; ++nt) {
        const int c = nt * 16 + mr;
        float s = 0.f, sq = 0.f;
#pragma unroll
        for (int r = 0; r < 4; ++r) {
            const int q = wv * 16 + qd * 4 + r;
            if (q < 49) { const float v = oacc[nt][r]; s += v; sq += v * v; }
        }
        s += __shfl_xor(s, 16); sq += __shfl_xor(sq, 16);
        s += __shfl_xor(s, 32); sq += __shfl_xor(sq, 32);
        if (qd == 0) { atomicAdd(&bnacc[c], s); atomicAdd(&bnacc[128 + c], sq); }
    }
    __syncthreads();   // b5: Ps/Vt reads + atomics done -> Os overlay safe

    // ---- O -> LDS [64][136] ----
#pragma unroll
    for (int nt = 0; nt < 8; ++nt) {
        const int c = nt * 16 + mr;
#pragma unroll
        for (int r = 0; r < 4; ++r) {
            const int q = wv * 16 + qd * 4 + r;
            Os[q * 136 + c] = (bf16_t)oacc[nt][r];
        }
    }
    __syncthreads();   // b6

    // ---- coalesced uint4 stores + BN partial out ----
    for (int idx = tid; idx < 49 * 16; idx += 256) {
        const int row = idx >> 4, u = idx & 15;
        const int n = (wy * 7 + row / 7) * 56 + wx * 7 + (row % 7);
        *(uint4*)(og + ((size_t)b * N_TOK + n) * CH + u * 8) =
            *(const uint4*)(&Os[row * 136 + u * 8]);
    }
    partial[(size_t)blk * 256 + tid] = bnacc[tid];
}

// ---------------------------------------------------------------------------
__global__ __launch_bounds__(256)
void bnreduce_k(const float* __restrict__ partial, float* __restrict__ accum)
{
    const int t = threadIdx.x;
    const int r0 = blockIdx.x * 16;
    float s = 0.f;
#pragma unroll
    for (int r = 0; r < 16; ++r) s += partial[(size_t)(r0 + r) * 256 + t];
    atomicAdd(&accum[t], s);
}

__global__ __launch_bounds__(256)
void bnstats2_k(const bf16_t* __restrict__ att, const float* __restrict__ g1,
                const float* __restrict__ b1, float* __restrict__ accum)
{
    __shared__ float ls[256], lq[256];
    const int c = threadIdx.x & 127;
    const int half = threadIdx.x >> 7;
    const float m = accum[c] * (1.f / (float)M_TOT);
    const float var = accum[128 + c] * (1.f / (float)M_TOT) - m * m;
    const float rstd = rsqrtf(var + 1e-5f);
    const float scl = g1[c] * rstd;
    const float sh = b1[c] - m * scl;
    const size_t rowbase = (size_t)blockIdx.x * 196;
    float s = 0.f, sq = 0.f;
    for (int r = half; r < 196; r += 2) {
        float z = fmaxf(0.f, bf2f(att[(rowbase + r) * CH + c]) * scl + sh);
        s += z; sq += z * z;
    }
    ls[threadIdx.x] = s; lq[threadIdx.x] = sq;
    __syncthreads();
    if (threadIdx.x < 128) {
        atomicAdd(&accum[256 + c], ls[threadIdx.x] + ls[threadIdx.x + 128]);
        atomicAdd(&accum[384 + c], lq[threadIdx.x] + lq[threadIdx.x + 128]);
    }
}

__global__ void bnparams_k(const float* __restrict__ accum,
                           const float* __restrict__ g1, const float* __restrict__ b1,
                           const float* __restrict__ g2, const float* __restrict__ b2,
                           float* __restrict__ bnp)
{
    const int c = threadIdx.x;
    const float inv = 1.f / (float)M_TOT;
    float m1 = accum[c] * inv;
    float v1 = accum[128 + c] * inv - m1 * m1;
    float rs1 = rsqrtf(v1 + 1e-5f);
    float s1 = g1[c] * rs1;
    float sh1 = b1[c] - m1 * s1;
    float m2 = accum[256 + c] * inv;
    float v2 = accum[384 + c] * inv - m2 * m2;
    float rs2 = rsqrtf(v2 + 1e-5f);
    float s2 = g2[c] * rs2;
    float sh2 = b2[c] - m2 * s2;
    bnp[c] = s1; bnp[128 + c] = sh1; bnp[256 + c] = s2; bnp[384 + c] = sh2;
}

__global__ void zero_k(float* __restrict__ p) { p[threadIdx.x] = 0.f; }

// ---------------------------------------------------------------------------
extern "C" void kernel_launch(void* const* d_in, const int* in_sizes, int n_in,
                              void* d_out, int out_size, void* d_ws, size_t ws_size,
                              hipStream_t stream)
{
    (void)in_sizes; (void)n_in; (void)out_size; (void)ws_size;
    const float* x     = (const float*)d_in[0];
    const float* fc1_w = (const float*)d_in[1];
    const float* fc1_b = (const float*)d_in[2];
    const float* fc2_w = (const float*)d_in[3];
    const float* fc2_b = (const float*)d_in[4];
    const float* fc3_w = (const float*)d_in[5];
    const float* fc3_b = (const float*)d_in[6];
    const float* fc4_w = (const float*)d_in[7];
    const float* fc4_b = (const float*)d_in[8];
    const float* fc5_w = (const float*)d_in[9];
    const float* fc5_b = (const float*)d_in[10];
    const float* fc6_w = (const float*)d_in[11];
    const float* fc6_b = (const float*)d_in[12];
    const float* ln_w  = (const float*)d_in[13];
    const float* ln_b  = (const float*)d_in[14];
    const float* q_w   = (const float*)d_in[15];
    const float* q_b   = (const float*)d_in[16];
    const float* k_w   = (const float*)d_in[17];
    const float* k_b   = (const float*)d_in[18];
    const float* v_w   = (const float*)d_in[19];
    const float* v_b   = (const float*)d_in[20];
    const float* bn1_g = (const float*)d_in[21];
    const float* bn1_b = (const float*)d_in[22];
    const float* bn2_g = (const float*)d_in[23];
    const float* bn2_b = (const float*)d_in[24];

    char* ws = (char*)d_ws;
    const size_t SZB = (size_t)M_TOT * CH * sizeof(bf16_t); // 25.7 MB
    bf16_t* bufA = (bf16_t*)(ws);            // xT -> attn out
    bf16_t* bufB = (bf16_t*)(ws + SZB);      // y3T -> x1
    bf16_t* bufC = (bf16_t*)(ws + 2 * SZB);  // x_1+x
    bf16_t* bufD = (bf16_t*)(ws + 3 * SZB);  // x_2+x
    bf16_t* xbf  = (bf16_t*)(ws + 4 * SZB);  // bf16 copy of x
    float*  rs1  = (float*)(ws + 5 * SZB);                 // [2*M] branch-1 partials
    float*  rs2  = rs1 + 2 * M_TOT;                        // [2*M] branch-2 partials
    float*  accum = rs2 + 2 * M_TOT;
    float*  bnp  = accum + 512;
    float*  partial = bnp + 512;             // [2048][256] (2 MB)
    bf16_t* wbuf = (bf16_t*)(partial + 2048 * 256); // preconverted weights (0.36 MB)

    const dim3 blk(256);
    const int GG = M_TOT / 64; // 1568

    zero_k<<<1, 512, 0, stream>>>(accum);
    wcvt_k<<<44, blk, 0, stream>>>(fc1_w, fc2_w, fc3_w, fc4_w, fc5_w, fc6_w,
                                   q_w, k_w, v_w, wbuf);
    transpose_k<<<GG, blk, 0, stream>>>(x, bufA, xbf);
    // branch 1 FUSED: fc1 (H-roll +c) + GELU + fc2 (W-roll +c) + x -> bufC; rs1
    fc12_k<<<B_SZ * 56, blk, 0, stream>>>(
        bufA, xbf, wbuf + WOFF_FC1, fc1_b, wbuf + WOFF_FC2, fc2_b, bufC, rs1);
    // branch 2: fc3 (W-roll -c) + GELU -> y3T [C,N]
    gemm_k<A_WROLL, 1, E_GELU, 1, 1, 0, 0><<<GG, blk, 0, stream>>>(
        bufA, nullptr, wbuf + WOFF_FC3, fc3_b, nullptr, nullptr, nullptr, nullptr,
        nullptr, nullptr, bufB);
    // fc4 (H-roll +c on y3T) + x -> bufD; rs2 partials
    gemm_k<A_FLAT, 1, E_RES, 0, 0, 0, 1><<<GG, blk, 0, stream>>>(
        bufB, nullptr, wbuf + WOFF_FC4, fc4_b, xbf, nullptr, nullptr, nullptr,
        nullptr, rs2, bufD);
    // fc5: LN (stats from rs1+rs2) + (+x) -> bufB = x1
    gemm_k<A_LN, 2, E_RES, 0, 0, 0, 0><<<GG, blk, 0, stream>>>(
        bufC, bufD, wbuf + WOFF_FC5, fc5_b, xbf, rs1, ln_w, ln_b,
        rs2, nullptr, bufB);
    // FUSED qkv + window attention (+ BN pass-1 partials) -> bufA
    qkvattn_k<<<B_SZ * 64, blk, 0, stream>>>(xbf, wbuf, q_b, k_b, v_b, bufA, partial);
    bnreduce_k<<<128, blk, 0, stream>>>(partial, accum);
    bnstats2_k<<<512, blk, 0, stream>>>(bufA, bn1_g, bn1_b, accum);
    bnparams_k<<<1, 128, 0, stream>>>(accum, bn1_g, bn1_b, bn2_g, bn2_b, bnp);
    // fc6 on [x1 | bn2(relu(bn1(att)))] -> d_out (f32)
    gemm_k<A_BN, 2, E_BIAS, 0, 0, 1, 0><<<GG, blk, 0, stream>>>(
        bufB, bufA, wbuf + WOFF_FC6, fc6_b, nullptr, nullptr, nullptr, nullptr,
        bnp, nullptr, d_out);
}